// Round 8
// baseline (195.067 us; speedup 1.0000x reference)
//
#include <hip/hip_runtime.h>
#include <hip/hip_bf16.h>

// N,C,K,P,Q,PS = 32,128,128,64,64,3
#define NN 32
#define CCH 128
#define KK 128
#define PP 64
#define QQ 64

typedef __bf16 bf16x8 __attribute__((ext_vector_type(8)));
typedef float f32x16 __attribute__((ext_vector_type(16)));
typedef float f32x4 __attribute__((ext_vector_type(4)));

// Workspace: only Wf (prep_x fused into conv_main since R7):
//   Wf: [8 cc][9 t][4 kb][64 lane][8 bf16] = 294,912 B

// ---------- prep: W -> Wf fragment order (unchanged — verified) ----------
__global__ __launch_bounds__(256) void prep_w(const float* __restrict__ W,
                                              __bf16* __restrict__ Wf) {
    const int id = blockIdx.x * 256 + threadIdx.x;  // 18432
    const int lane = id & 63;
    const int r1   = id >> 6;
    const int kb   = r1 & 3;
    const int r2   = r1 >> 2;
    const int t    = r2 % 9;
    const int cc   = r2 / 9;

    const int k  = kb * 32 + (lane & 31);
    const int c0 = cc * 16 + (lane >> 5) * 8;

    bf16x8 o;
#pragma unroll
    for (int j = 0; j < 8; ++j)
        o[j] = (__bf16)W[(size_t)k * (CCH * 9) + (size_t)(c0 + j) * 9 + t];
    ((bf16x8*)Wf)[id] = o;
}

// ---------- main: FUSED implicit GEMM conv, T14 async-split staging ----------
// R7: fused stage was load->wait->cvt->write BEFORE compute -> full L3 latency
// exposed every cc (conv 69->83). R8: split stage into
//   stage_load (issue 24 loads, no wait)  ->  compute(cc)  ->  stage_write
// fv loads drain for free under compute's own a-load waits (in-order vmcnt).
// Register budget: fv(24) paid for by dropping the a-rotation (-24 VGPR);
// compute is oi-major, reloads A per oi (L2 reads proven free in R4/R5).
// Also: nontemporal per loads (stop evicting L3-resident x), s_setprio around
// MFMA groups (2 unsynced blocks/CU = T5 role diversity).
#define XPITCH 2112  // bytes per padded x row in LDS (66 * 32)
#define XROWS  6
#define XBYTES (XROWS * XPITCH)  // 12,672

__global__ __launch_bounds__(256, 2) void conv_main(const float* __restrict__ x,
                                                    const __bf16* __restrict__ Wf,
                                                    const float* __restrict__ per,
                                                    float* __restrict__ out) {
    __shared__ __align__(16) char xlds[2][XBYTES];   // 25,344
    __shared__ __align__(16) char scr_lds[4][4096];  // per-wave epilogue scratch

    const int tid  = threadIdx.x;
    const int lane = tid & 63;
    const int w    = tid >> 6;   // 0..3
    const int kbs  = w & 1;
    const int pb   = w >> 1;     // 0..1
    const int n    = blockIdx.y;
    const int p0   = blockIdx.x * 4;
    const int m    = lane & 31;
    const int half = lane >> 5;

    // zero the pad columns (q=-1 and q=64 slots) in BOTH buffers, once;
    // staging writes only bytes [32, 2080) per row, so pads stay zero.
    if (tid < 24) {
        int row = tid >> 2, part = tid & 3;
        int off = row * XPITCH + (part >> 1) * 2080 + (part & 1) * 16;
        *(f32x4*)(xlds[0] + off) = f32x4{0.f, 0.f, 0.f, 0.f};
        *(f32x4*)(xlds[1] + off) = f32x4{0.f, 0.f, 0.f, 0.f};
    }

    f32x16 acc[2][2][2];  // [oi][kb][qb]
#pragma unroll
    for (int a = 0; a < 2; ++a)
#pragma unroll
        for (int b = 0; b < 2; ++b)
#pragma unroll
            for (int c = 0; c < 2; ++c)
#pragma unroll
                for (int e = 0; e < 16; ++e) acc[a][b][c][e] = 0.f;

    const float* xn = x + (size_t)n * CCH * PP * QQ;

    // stage_load: issue 24 x-loads (3 tasks x 8 c-strided f32), NO wait.
    // Each wave-instr = contiguous 256 B (lane = q). fv stays in flight
    // across compute; drained for free by compute's a-load waits.
    auto stage_load = [&](int ccn, float (&fv)[3][8]) {
        const float* xs = xn + (size_t)ccn * 16 * PP * QQ;
#pragma unroll
        for (int it = 0; it < 3; ++it) {
            int t4  = it * 4 + w;        // task id, wave-uniform
            int row = t4 >> 1;           // 0..5
            int ch  = t4 & 1;            // c-half
            int r   = p0 - 1 + row;
            int rc  = r < 0 ? 0 : (r > 63 ? 63 : r);
            const float* src = xs + ((size_t)(ch * 8) * PP + rc) * QQ + lane;
#pragma unroll
            for (int j = 0; j < 8; ++j) fv[it][j] = src[(size_t)j * PP * QQ];
        }
    };
    // stage_write: cvt f32->bf16, pack, 3x ds_write_b128 (layout verified R7)
    auto stage_write = [&](int buf, const float (&fv)[3][8]) {
#pragma unroll
        for (int it = 0; it < 3; ++it) {
            int t4  = it * 4 + w;
            int row = t4 >> 1;
            int ch  = t4 & 1;
            bf16x8 o;
#pragma unroll
            for (int j = 0; j < 8; ++j) o[j] = (__bf16)fv[it][j];
            *(bf16x8*)(xlds[buf] + row * XPITCH + 32 + lane * 32 + ch * 16) = o;
        }
    };

    // A fragment base (verified R4/R5): frag id = cc*2304 + (t*4 + kbs*2+kb)*64 + lane
    const bf16x8* wg = (const bf16x8*)Wf + kbs * 128 + lane;

    // oi-major compute: A reloaded per oi (no rotation; frees 24 VGPR for fv)
    auto compute = [&](int buf, int cc) {
        const char* xbase = xlds[buf];
        const bf16x8* wc = wg + (size_t)cc * 2304;

#pragma unroll
        for (int oi = 0; oi < 2; ++oi) {
#pragma unroll
            for (int tr = 0; tr < 3; ++tr) {
                const int ri = oi + tr;
                const int r  = p0 + pb * 2 + ri - 1;            // input row
                const bool rok = ((unsigned)r < (unsigned)PP);  // wave-uniform
                if (rok) {
                    const char* rbase = xbase + (pb * 2 + ri) * XPITCH + half * 16;
                    bf16x8 b[3][2], a[3][2];
#pragma unroll
                    for (int dq = 0; dq < 3; ++dq)
#pragma unroll
                        for (int qb = 0; qb < 2; ++qb)
                            b[dq][qb] = *(const bf16x8*)(rbase + (qb * 32 + m + dq) * 32);
#pragma unroll
                    for (int dq = 0; dq < 3; ++dq)
#pragma unroll
                        for (int kb = 0; kb < 2; ++kb)
                            a[dq][kb] = wc[((tr * 3 + dq) * 4 + kb) * 64];  // L2 hit
                    __builtin_amdgcn_s_setprio(1);
#pragma unroll
                    for (int dq = 0; dq < 3; ++dq)
#pragma unroll
                        for (int kb = 0; kb < 2; ++kb)
#pragma unroll
                            for (int qb = 0; qb < 2; ++qb)
                                acc[oi][kb][qb] = __builtin_amdgcn_mfma_f32_32x32x16_bf16(
                                    a[dq][kb], b[dq][qb], acc[oi][kb][qb], 0, 0, 0);
                    __builtin_amdgcn_s_setprio(0);
                }
            }
        }
    };

    // prologue: one exposed staging wait
    {
        float fv[3][8];
        stage_load(0, fv);
        stage_write(0, fv);
    }
    __syncthreads();

    for (int cc = 0; cc < 7; ++cc) {
        float fv[3][8];
        stage_load(cc + 1, fv);        // issue, no wait
        compute(cc & 1, cc);           // fv drains under this
        stage_write((cc + 1) & 1, fv); // near-instant wait + cvt + ds_write
        __syncthreads();
    }

    // ---- epilogue (verified R3/R4 mapping; per loads nontemporal) ----
    auto tile_addr = [&](int it, int j) -> size_t {
        int oi = it >> 2, kbi = (it >> 1) & 1, qb = it & 1;
        int prow = p0 + pb * 2 + oi;
        int k = (kbs * 2 + kbi) * 32 + (lane >> 3) + j * 8;
        int q = qb * 32 + (lane & 7) * 4;
        return (((size_t)n * KK + k) * PP + prow) * QQ + q;
    };

    float* scr = (float*)scr_lds[w];  // private per wave

    auto process = [&](int it, f32x4 (&pv)[4]) {
        int oi = it >> 2, kbi = (it >> 1) & 1, qb = it & 1;
        f32x16 v = acc[oi][kbi][qb];
#pragma unroll
        for (int r = 0; r < 16; ++r) {
            int kl = (r & 3) + 8 * (r >> 2) + 4 * half;
            scr[kl * 32 + ((((m >> 2) ^ (kl & 7)) << 2) | (m & 3))] = v[r];
        }
        // same-wave LDS RAW: compiler inserts lgkmcnt wait
#pragma unroll
        for (int j = 0; j < 4; ++j) {
            int kl = (lane >> 3) + j * 8;
            f32x4 d = *(const f32x4*)(scr + kl * 32 + (((lane & 7) ^ (kl & 7)) << 2));
            f32x4 s = d + pv[j];
            __builtin_nontemporal_store(s, (f32x4*)(out + tile_addr(it, j)));
        }
    };

    // ---- peeled cc=7 with depth-1 nontemporal per prefetch ----
    f32x4 pv0[4], pv1[4];
#pragma unroll
    for (int j = 0; j < 4; ++j)
        pv0[j] = __builtin_nontemporal_load((const f32x4*)(per + tile_addr(0, j)));

    compute(1, 7);  // buf 1, staged during cc=6 iteration

#pragma unroll
    for (int itp = 0; itp < 4; ++itp) {
        const int itA = itp * 2, itB = itp * 2 + 1;
#pragma unroll
        for (int j = 0; j < 4; ++j)
            pv1[j] = __builtin_nontemporal_load((const f32x4*)(per + tile_addr(itB, j)));
        process(itA, pv0);
        if (itp < 3) {
#pragma unroll
            for (int j = 0; j < 4; ++j)
                pv0[j] = __builtin_nontemporal_load((const f32x4*)(per + tile_addr(itA + 2, j)));
        }
        process(itB, pv1);
    }
}

extern "C" void kernel_launch(void* const* d_in, const int* in_sizes, int n_in,
                              void* d_out, int out_size, void* d_ws, size_t ws_size,
                              hipStream_t stream) {
    const float* x   = (const float*)d_in[0];  // [32][128][64][64]
    const float* W   = (const float*)d_in[1];  // [128][1152]
    const float* per = (const float*)d_in[2];  // [32][128][64][64]
    float* out = (float*)d_out;

    __bf16* Wf = (__bf16*)d_ws;  // 294,912 B

    prep_w<<<dim3(72), 256, 0, stream>>>(W, Wf);
    conv_main<<<dim3(PP / 4, NN), 256, 0, stream>>>(x, Wf, per, out);
}